// Round 1
// baseline (388.779 us; speedup 1.0000x reference)
//
#include <hip/hip_runtime.h>
#include <hip/hip_fp16.h>

typedef unsigned int u32;

#define OUTD  4096
#define BATCH 4096
#define DEXC  8192
#define DINH  2048
#define KEXC  32
#define KINH  16
#define NB    8
#define LDS_BYTES (DEXC * 16 + DINH * 16)   // 131072 + 32768 = 163840 (full 160 KiB)

// ---------------- top-k + exp + pack kernel ----------------
// One block per output row. Finds top-K of pre_w[o,:], emits packed records
// (fp16(exp(pre_w)) << 16) | col_idx, in k-major-interleaved layout:
// dword index = ((r>>2)*OUTD + o)*4 + (r&3)  → main kernel loads uint4 at [kk*OUTD + o].
template<int IN, int K, int VPT>
__global__ __launch_bounds__(256)
void topk_pack_kernel(const float* __restrict__ pw, u32* __restrict__ pack_out, float T0) {
  constexpr int CAP = 1024;
  __shared__ float s_val[CAP];
  __shared__ int   s_idx[CAP];
  __shared__ int   s_red[4];
  __shared__ int   s_total;
  __shared__ int   s_cnt;

  const int tid = threadIdx.x;
  const int o   = blockIdx.x;
  const float* row = pw + (size_t)o * IN;

  float v[VPT];
#pragma unroll
  for (int c = 0; c < VPT; ++c) v[c] = row[tid + c * 256];

  // find threshold T with K <= count(>T) <= CAP. T0 chosen so this holds with
  // P ~ 99.6% on N(0,1) rows; fallback steps handle the rest. Guaranteed to
  // terminate with count >= K (last-resort T = -1e30, collect clamped at CAP).
  float T = T0;
  int C = 0;
  for (int iter = 0; iter < 50; ++iter) {
    int cnt = 0;
#pragma unroll
    for (int c = 0; c < VPT; ++c) cnt += (v[c] > T) ? 1 : 0;
#pragma unroll
    for (int off = 32; off >= 1; off >>= 1) cnt += __shfl_down(cnt, off, 64);
    if ((tid & 63) == 0) s_red[tid >> 6] = cnt;
    __syncthreads();
    if (tid == 0) s_total = s_red[0] + s_red[1] + s_red[2] + s_red[3];
    __syncthreads();
    C = s_total;
    if (C >= K && C <= CAP) break;
    if (iter >= 47)    T = -1e30f;
    else if (C < K)    T -= 0.75f;
    else               T += 0.375f;
    __syncthreads();
  }

  // collect candidates > T into LDS (compacted)
  if (tid == 0) s_cnt = 0;
  __syncthreads();
#pragma unroll
  for (int c = 0; c < VPT; ++c) {
    if (v[c] > T) {
      int p = atomicAdd(&s_cnt, 1);
      if (p < CAP) { s_val[p] = v[c]; s_idx[p] = tid + c * 256; }
    }
  }
  __syncthreads();
  C = s_cnt < CAP ? s_cnt : CAP;

  // O(C^2) rank select; tie-break by lower index (matches lax.top_k set).
  // Ranks 0..K-1 are a bijection, so every output slot is written exactly once.
  for (int t = tid; t < C; t += 256) {
    float mv = s_val[t];
    int   mi = s_idx[t];
    int   r  = 0;
    for (int q = 0; q < C; ++q) {
      float qv = s_val[q];
      r += ((qv > mv) || (qv == mv && s_idx[q] < mi)) ? 1 : 0;
    }
    if (r < K) {
      float w  = __expf(mv);                       // w <= exp(~5.6) ~ 270, fits fp16
      u32   hb = (u32)__half_as_ushort(__float2half(w));
      pack_out[((r >> 2) * OUTD + o) * 4 + (r & 3)] = (hb << 16) | (u32)mi;
    }
  }
}

// ---------------- main gather kernel ----------------
__device__ __forceinline__ u32 pack2(float a, float b) {
  __half2 h = __floats2half2_rn(a, b);
  return __builtin_bit_cast(u32, h);
}

__device__ __forceinline__ void accum4(u32 u, const uint4* __restrict__ lds, __half2 acc[4]) {
  const u32 j  = u & 0xFFFFu;
  const u32 wb = __builtin_amdgcn_perm(u, u, 0x03020302u);  // hi16 replicated: {w,w}
  const __half2 w2 = __builtin_bit_cast(__half2, wb);
  const uint4 xf = lds[j];                                  // ds_read_b128: x[j][b0..b7] fp16
  acc[0] = __hfma2(w2, __builtin_bit_cast(__half2, xf.x), acc[0]);
  acc[1] = __hfma2(w2, __builtin_bit_cast(__half2, xf.y), acc[1]);
  acc[2] = __hfma2(w2, __builtin_bit_cast(__half2, xf.z), acc[2]);
  acc[3] = __hfma2(w2, __builtin_bit_cast(__half2, xf.w), acc[3]);
}

__global__ __launch_bounds__(1024, 4)
void dendrite_main(const float* __restrict__ xe, const float* __restrict__ xi,
                   const uint4* __restrict__ pe4, const uint4* __restrict__ pi4,
                   float* __restrict__ out) {
  extern __shared__ char smem[];
  uint4* ldsE = (uint4*)smem;                  // [DEXC] : x_exc[j][b0..b7] fp16, 128 KiB
  uint4* ldsI = (uint4*)(smem + DEXC * 16);    // [DINH] : x_inh, 32 KiB
  const int tid = threadIdx.x;
  const int b0  = blockIdx.x * NB;

  // ---- stage 8 batch rows, f32 -> fp16, transposed [j][b] ----
  // lane j consecutive -> global loads coalesced per row, ds_write_b128 conflict-free
#pragma unroll
  for (int it = 0; it < DEXC / 1024; ++it) {
    const int j = tid + it * 1024;
    float v[NB];
#pragma unroll
    for (int b = 0; b < NB; ++b) v[b] = xe[(size_t)(b0 + b) * DEXC + j];
    uint4 f;
    f.x = pack2(v[0], v[1]); f.y = pack2(v[2], v[3]);
    f.z = pack2(v[4], v[5]); f.w = pack2(v[6], v[7]);
    ldsE[j] = f;
  }
#pragma unroll
  for (int it = 0; it < DINH / 1024; ++it) {
    const int j = tid + it * 1024;
    float v[NB];
#pragma unroll
    for (int b = 0; b < NB; ++b) v[b] = xi[(size_t)(b0 + b) * DINH + j];
    uint4 f;
    f.x = pack2(v[0], v[1]); f.y = pack2(v[2], v[3]);
    f.z = pack2(v[4], v[5]); f.w = pack2(v[6], v[7]);
    ldsI[j] = f;
  }
  __syncthreads();

  // ---- gather phase: each thread owns 4 outputs (lanes -> consecutive o) ----
#pragma unroll
  for (int r = 0; r < OUTD / 1024; ++r) {
    const int o = tid + r * 1024;
    uint4 pkE[KEXC / 4];
#pragma unroll
    for (int kk = 0; kk < KEXC / 4; ++kk) pkE[kk] = pe4[kk * OUTD + o];   // coalesced 16B/lane
    uint4 pkI[KINH / 4];
#pragma unroll
    for (int kk = 0; kk < KINH / 4; ++kk) pkI[kk] = pi4[kk * OUTD + o];

    const __half2 z = __builtin_bit_cast(__half2, 0u);
    __half2 e[4]  = {z, z, z, z};
    __half2 ia[4] = {z, z, z, z};
#pragma unroll
    for (int kk = 0; kk < KEXC / 4; ++kk) {
      accum4(pkE[kk].x, ldsE, e); accum4(pkE[kk].y, ldsE, e);
      accum4(pkE[kk].z, ldsE, e); accum4(pkE[kk].w, ldsE, e);
    }
#pragma unroll
    for (int kk = 0; kk < KINH / 4; ++kk) {
      accum4(pkI[kk].x, ldsI, ia); accum4(pkI[kk].y, ldsI, ia);
      accum4(pkI[kk].z, ldsI, ia); accum4(pkI[kk].w, ldsI, ia);
    }
    // ---- epilogue: out = e / (1 + i), coalesced stores per batch row ----
#pragma unroll
    for (int d = 0; d < 4; ++d) {
      const float2 ev = __half22float2(e[d]);
      const float2 iv = __half22float2(ia[d]);
      out[(size_t)(b0 + 2 * d    ) * OUTD + o] = ev.x * __builtin_amdgcn_rcpf(1.0f + iv.x);
      out[(size_t)(b0 + 2 * d + 1) * OUTD + o] = ev.y * __builtin_amdgcn_rcpf(1.0f + iv.y);
    }
  }
}

extern "C" void kernel_launch(void* const* d_in, const int* in_sizes, int n_in,
                              void* d_out, int out_size, void* d_ws, size_t ws_size,
                              hipStream_t stream) {
  const float* xe  = (const float*)d_in[0];   // x_exc  [4096][8192]
  const float* xi  = (const float*)d_in[1];   // x_inh  [4096][2048]
  const float* pwe = (const float*)d_in[2];   // pre_w_exc [4096][8192]
  const float* pwi = (const float*)d_in[3];   // pre_w_inh [4096][2048]
  u32* packE = (u32*)d_ws;                    // OUTD*KEXC u32 = 512 KiB
  u32* packI = packE + OUTD * KEXC;           // OUTD*KINH u32 = 256 KiB (ws needs 768 KiB)

  (void)hipFuncSetAttribute((const void*)dendrite_main,
                            hipFuncAttributeMaxDynamicSharedMemorySize, LDS_BYTES);

  topk_pack_kernel<DEXC, KEXC, DEXC / 256><<<OUTD, 256, 0, stream>>>(pwe, packE, 2.5f);
  topk_pack_kernel<DINH, KINH, DINH / 256><<<OUTD, 256, 0, stream>>>(pwi, packI, 2.0f);
  dendrite_main<<<BATCH / NB, 1024, LDS_BYTES, stream>>>(
      xe, xi, (const uint4*)packE, (const uint4*)packI, (float*)d_out);
}

// Round 2
// 368.396 us; speedup vs baseline: 1.0553x; 1.0553x over previous
//
#include <hip/hip_runtime.h>
#include <hip/hip_fp16.h>

typedef unsigned int u32;

#define OUTD  4096
#define BATCH 4096
#define DEXC  8192
#define DINH  2048
#define KEXC  32
#define KINH  16
#define NB    4
#define LDS_BYTES (DEXC * 8 + DINH * 8)   // 65536 + 16384 = 81920 B -> 2 blocks/CU
constexpr int CAP = 1024;

// ---------------- fused top-k + exp + pack ----------------
// One block per output row (exc rows then inh rows in one grid so the two
// problems overlap). Emits (fp16(exp(w))<<16)|idx in k-major-interleaved
// layout: dword index ((r>>2)*OUTD+o)*4+(r&3) -> main loads uint4 at kk*OUTD+o.
template<int IN, int K>
__device__ __forceinline__ void topk_row(const float* __restrict__ pw, u32* __restrict__ pack_out,
                                         int o, float T0,
                                         float* s_val, int* s_idx, int* s_red, int* s_misc) {
  constexpr int V4 = IN / 1024;            // float4 per thread
  const int tid = threadIdx.x;
  const float4* row = (const float4*)(pw + (size_t)o * IN);

  float4 v[V4];
#pragma unroll
  for (int c = 0; c < V4; ++c) v[c] = row[tid + c * 256];

  // threshold search: K <= count(>T) <= CAP (T0 statistically right ~99.5% of rows)
  float T = T0;
  int C = 0;
  for (int iter = 0; iter < 50; ++iter) {
    int cnt = 0;
#pragma unroll
    for (int c = 0; c < V4; ++c)
      cnt += (v[c].x > T) + (v[c].y > T) + (v[c].z > T) + (v[c].w > T);
#pragma unroll
    for (int off = 32; off >= 1; off >>= 1) cnt += __shfl_down(cnt, off, 64);
    if ((tid & 63) == 0) s_red[tid >> 6] = cnt;
    __syncthreads();
    if (tid == 0) s_misc[0] = s_red[0] + s_red[1] + s_red[2] + s_red[3];
    __syncthreads();
    C = s_misc[0];
    if (C >= K && C <= CAP) break;
    if (iter >= 47)    T = -1e30f;
    else if (C < K)    T -= 0.75f;
    else               T += 0.375f;
    __syncthreads();
  }

  if (tid == 0) s_misc[1] = 0;
  __syncthreads();
#pragma unroll
  for (int c = 0; c < V4; ++c) {
    const float vv[4] = {v[c].x, v[c].y, v[c].z, v[c].w};
#pragma unroll
    for (int q = 0; q < 4; ++q) {
      if (vv[q] > T) {
        int p = atomicAdd(&s_misc[1], 1);
        if (p < CAP) { s_val[p] = vv[q]; s_idx[p] = (tid + c * 256) * 4 + q; }
      }
    }
  }
  __syncthreads();
  C = s_misc[1] < CAP ? s_misc[1] : CAP;

  // O(C^2) rank select (C ~ 50); tie-break by lower index; ranks are a bijection.
  for (int t = tid; t < C; t += 256) {
    const float mv = s_val[t];
    const int   mi = s_idx[t];
    int r = 0;
    for (int q = 0; q < C; ++q) {
      const float qv = s_val[q];
      r += ((qv > mv) || (qv == mv && s_idx[q] < mi)) ? 1 : 0;
    }
    if (r < K) {
      const float w = __expf(mv);
      const u32 hb = (u32)__half_as_ushort(__float2half(w));
      pack_out[((r >> 2) * OUTD + o) * 4 + (r & 3)] = (hb << 16) | (u32)mi;
    }
  }
}

__global__ __launch_bounds__(256)
void topk_both(const float* __restrict__ pwe, const float* __restrict__ pwi,
               u32* __restrict__ packE, u32* __restrict__ packI) {
  __shared__ float s_val[CAP];
  __shared__ int   s_idx[CAP];
  __shared__ int   s_red[4];
  __shared__ int   s_misc[2];
  if (blockIdx.x < OUTD)
    topk_row<DEXC, KEXC>(pwe, packE, blockIdx.x, 2.5f, s_val, s_idx, s_red, s_misc);
  else
    topk_row<DINH, KINH>(pwi, packI, blockIdx.x - OUTD, 2.0f, s_val, s_idx, s_red, s_misc);
}

// ---------------- main gather kernel ----------------
__device__ __forceinline__ u32 pack2f(float a, float b) {
  __half2 h = __floats2half2_rn(a, b);
  return __builtin_bit_cast(u32, h);
}

__device__ __forceinline__ void accum2(u32 u, const uint2* __restrict__ lds, __half2 acc[2]) {
  const u32 j  = u & 0xFFFFu;
  const u32 wb = __builtin_amdgcn_perm(u, u, 0x03020302u);  // {w,w} fp16 pair
  const __half2 w2 = __builtin_bit_cast(__half2, wb);
  const uint2 xf = lds[j];                                  // ds_read_b64: x[j][b0..b3] fp16
  acc[0] = __hfma2(w2, __builtin_bit_cast(__half2, xf.x), acc[0]);
  acc[1] = __hfma2(w2, __builtin_bit_cast(__half2, xf.y), acc[1]);
}

__global__ __launch_bounds__(1024, 8)
void dendrite_main(const float* __restrict__ xe, const float* __restrict__ xi,
                   const uint4* __restrict__ pe4, const uint4* __restrict__ pi4,
                   float* __restrict__ out) {
  extern __shared__ char smem[];
  uint2* ldsE = (uint2*)smem;                  // [DEXC] : x_exc[j][b0..b3] fp16, 64 KiB
  uint2* ldsI = (uint2*)(smem + DEXC * 8);     // [DINH] : 16 KiB
  const int tid = threadIdx.x;
  const int b0  = blockIdx.x * NB;

  // ---- stage 4 batch rows, f32 -> fp16, transposed [j][b], float4 loads ----
#pragma unroll
  for (int it = 0; it < DEXC / 4096; ++it) {   // 2 iters, 4 j per thread
    const int j4 = tid + it * 1024;
    float4 r0 = ((const float4*)(xe + (size_t)(b0 + 0) * DEXC))[j4];
    float4 r1 = ((const float4*)(xe + (size_t)(b0 + 1) * DEXC))[j4];
    float4 r2 = ((const float4*)(xe + (size_t)(b0 + 2) * DEXC))[j4];
    float4 r3 = ((const float4*)(xe + (size_t)(b0 + 3) * DEXC))[j4];
    uint2* dst = ldsE + j4 * 4;
    dst[0] = {pack2f(r0.x, r1.x), pack2f(r2.x, r3.x)};
    dst[1] = {pack2f(r0.y, r1.y), pack2f(r2.y, r3.y)};
    dst[2] = {pack2f(r0.z, r1.z), pack2f(r2.z, r3.z)};
    dst[3] = {pack2f(r0.w, r1.w), pack2f(r2.w, r3.w)};
  }
  if (tid < DINH / 4) {                        // 512 threads, 1 iter
    const int j4 = tid;
    float4 r0 = ((const float4*)(xi + (size_t)(b0 + 0) * DINH))[j4];
    float4 r1 = ((const float4*)(xi + (size_t)(b0 + 1) * DINH))[j4];
    float4 r2 = ((const float4*)(xi + (size_t)(b0 + 2) * DINH))[j4];
    float4 r3 = ((const float4*)(xi + (size_t)(b0 + 3) * DINH))[j4];
    uint2* dst = ldsI + j4 * 4;
    dst[0] = {pack2f(r0.x, r1.x), pack2f(r2.x, r3.x)};
    dst[1] = {pack2f(r0.y, r1.y), pack2f(r2.y, r3.y)};
    dst[2] = {pack2f(r0.z, r1.z), pack2f(r2.z, r3.z)};
    dst[3] = {pack2f(r0.w, r1.w), pack2f(r2.w, r3.w)};
  }
  __syncthreads();

  // ---- gather: each thread owns 4 outputs (lanes -> consecutive o) ----
#pragma unroll
  for (int r = 0; r < OUTD / 1024; ++r) {
    const int o = tid + r * 1024;
    const __half2 z = __builtin_bit_cast(__half2, 0u);
    __half2 e[2]  = {z, z};
    __half2 ia[2] = {z, z};
#pragma unroll
    for (int kk = 0; kk < KEXC / 4; ++kk) {
      const uint4 p = pe4[kk * OUTD + o];      // coalesced 16 B/lane
      accum2(p.x, ldsE, e); accum2(p.y, ldsE, e);
      accum2(p.z, ldsE, e); accum2(p.w, ldsE, e);
    }
#pragma unroll
    for (int kk = 0; kk < KINH / 4; ++kk) {
      const uint4 p = pi4[kk * OUTD + o];
      accum2(p.x, ldsI, ia); accum2(p.y, ldsI, ia);
      accum2(p.z, ldsI, ia); accum2(p.w, ldsI, ia);
    }
#pragma unroll
    for (int d = 0; d < 2; ++d) {
      const float2 ev = __half22float2(e[d]);
      const float2 iv = __half22float2(ia[d]);
      out[(size_t)(b0 + 2 * d    ) * OUTD + o] = ev.x * __builtin_amdgcn_rcpf(1.0f + iv.x);
      out[(size_t)(b0 + 2 * d + 1) * OUTD + o] = ev.y * __builtin_amdgcn_rcpf(1.0f + iv.y);
    }
  }
}

extern "C" void kernel_launch(void* const* d_in, const int* in_sizes, int n_in,
                              void* d_out, int out_size, void* d_ws, size_t ws_size,
                              hipStream_t stream) {
  const float* xe  = (const float*)d_in[0];   // x_exc  [4096][8192]
  const float* xi  = (const float*)d_in[1];   // x_inh  [4096][2048]
  const float* pwe = (const float*)d_in[2];   // pre_w_exc [4096][8192]
  const float* pwi = (const float*)d_in[3];   // pre_w_inh [4096][2048]
  u32* packE = (u32*)d_ws;                    // OUTD*KEXC u32 = 512 KiB
  u32* packI = packE + OUTD * KEXC;           // OUTD*KINH u32 = 256 KiB

  (void)hipFuncSetAttribute((const void*)dendrite_main,
                            hipFuncAttributeMaxDynamicSharedMemorySize, LDS_BYTES);

  topk_both<<<2 * OUTD, 256, 0, stream>>>(pwe, pwi, packE, packI);
  dendrite_main<<<BATCH / NB, 1024, LDS_BYTES, stream>>>(
      xe, xi, (const uint4*)packE, (const uint4*)packI, (float*)d_out);
}